// Round 10
// baseline (158.157 us; speedup 1.0000x reference)
//
#include <hip/hip_runtime.h>
#include <hip/hip_fp16.h>
#include <math.h>

// Problem constants (N=2, C=256, H=W=64, G=8, P=9, CG=32)
#define CC    256
#define HH    64
#define WW    64
#define HWSZ  4096
#define NPIX  8192
#define CT    16        // conv_in tile (pixels)
#define TT    16        // tail tile (pixels)
#define ASTR  264       // A-tile LDS row stride in fp16 elems (528 B)

typedef __attribute__((ext_vector_type(8))) _Float16 half8;
typedef __attribute__((ext_vector_type(4))) float f32x4;

__device__ __forceinline__ float silu_f(float x) { return x / (1.f + __expf(-x)); }

// fp32 -> fp16 (RNE), as raw short
__device__ __forceinline__ short f2h(float f) {
    __half h = __float2half(f);
    return *reinterpret_cast<short*>(&h);
}
__device__ __forceinline__ unsigned h2u(float a, float b) {
    __half2 h = __floats2half2_rn(a, b);
    return *reinterpret_cast<unsigned*>(&h);
}
__device__ __forceinline__ __half2 u2h(unsigned v) { return *reinterpret_cast<__half2*>(&v); }
__device__ __forceinline__ unsigned h2raw(__half2 h) { return *reinterpret_cast<unsigned*>(&h); }
// 4 packed fp16 -> float4
__device__ __forceinline__ float4 h2f4(uint2 u) {
    float2 a = __half22float2(u2h(u.x));
    float2 b = __half22float2(u2h(u.y));
    return make_float4(a.x, a.y, b.x, b.y);
}

// ---------------------------------------------------------------------------
// prepA: ONLY what k_conv_in needs (Wipb transpose, Wc1b copy, all scalars).
// 21 blocks x 256 threads.
__global__ __launch_bounds__(256) void k_prepA(
        const float* __restrict__ cw, const float* __restrict__ ipw,
        const float* __restrict__ dww,
        const float* __restrict__ offb, const float* __restrict__ maskb,
        const float* __restrict__ g1, const float* __restrict__ b1,
        const float* __restrict__ m1, const float* __restrict__ v1,
        const float* __restrict__ g2, const float* __restrict__ b2,
        const float* __restrict__ m2, const float* __restrict__ v2,
        short* __restrict__ Wc1b, short* __restrict__ Wipb,
        float* __restrict__ dwt,
        float* __restrict__ bh, float* __restrict__ sc1, float* __restrict__ sh1,
        float* __restrict__ sc2, float* __restrict__ sh2) {
    __shared__ float tile[64 * 65];
    int t = threadIdx.x, bt = blockIdx.x;
    int ct = t & 63, rb = t >> 6;             // rb 0..3
    if (bt < 16) {
        int sub = bt;
        int oT = (sub & 3) * 64, cT = (sub >> 2) * 64;
#pragma unroll
        for (int i = 0; i < 16; ++i) {
            int r = rb * 16 + i;              // c within tile
            tile[r * 65 + ct] = ipw[(cT + r) * CC + oT + ct];
        }
        __syncthreads();
#pragma unroll
        for (int i = 0; i < 16; ++i) {
            int r = rb * 16 + i;              // o within tile
            Wipb[(size_t)(oT + r) * CC + cT + ct] = f2h(tile[ct * 65 + r]);
        }
    } else if (bt < 20) {
        // Wc1b straight copy: 4 blocks x 16 iters x 256 thr x 4 = 65536
        int base = (bt - 16) * 16384;
#pragma unroll
        for (int i = 0; i < 16; ++i) {
            int idx = base + i * 1024 + t * 4;
            float4 v = *(const float4*)(cw + idx);
            *(uint2*)(Wc1b + idx) = make_uint2(h2u(v.x, v.y), h2u(v.z, v.w));
        }
    } else {
        int c = t;
#pragma unroll
        for (int j = 0; j < 9; ++j)
            dwt[j * CC + c] = dww[c * 9 + j];   // writes coalesced across lanes
        float bv = 0.f;
        if (c < 144) bv = offb[c];
        else if (c < 216) bv = maskb[c - 144];
        bh[c] = bv;
        float s1 = g1[c] * rsqrtf(v1[c] + 1e-3f);
        sc1[c] = s1; sh1[c] = b1[c] - m1[c] * s1;
        float s2 = g2[c] * rsqrtf(v2[c] + 1e-5f);
        sc2[c] = s2; sh2[c] = b2[c] - m2[c] * s2;
    }
}

// ---------------------------------------------------------------------------
// wave-level GEMM (fp16): 1 n-tile (16 outputs) per wave, K=256, A rows 0..15 in LDS
__device__ __forceinline__ void gemm1(const short* As, const short* __restrict__ Wb,
                                      int lane, int n0, f32x4* acc) {
    const int m = lane & 15, q = lane >> 4;
#pragma unroll
    for (int kk = 0; kk < 8; ++kk) {
        int c0 = kk * 32 + q * 8;
        half8 a = *(const half8*)(As + m * ASTR + c0);
        half8 b = *(const half8*)(Wb + (size_t)(n0 + m) * CC + c0);
        *acc = __builtin_amdgcn_mfma_f32_16x16x32_f16(a, b, *acc, 0, 0, 0);
    }
}

// ---------------------------------------------------------------------------
// conv1(1x1) + BN1 + SiLU -> ybf ; fused inproj -> xpb.
// CT=16: blocks 0..511 conv (2 blocks/CU -> 32 waves/CU); blocks 512..543
// piggy-backed prep of TAIL-ONLY weights (Whb/Wopb transposes).
__global__ __launch_bounds__(1024, 8) void k_conv_in(
        const float* __restrict__ x, const short* __restrict__ Wc1b,
        const short* __restrict__ Wipb, const float* __restrict__ sc1,
        const float* __restrict__ sh1, const float* __restrict__ ipb,
        const float* __restrict__ offw, const float* __restrict__ maskw,
        const float* __restrict__ opw,
        short* __restrict__ Whb, short* __restrict__ Wopb,
        short* __restrict__ ybf, short* __restrict__ xpb) {
    __shared__ __align__(16) short As[CT * ASTR];
    __shared__ float tile[64 * 65];
    int tid = threadIdx.x, lane = tid & 63, wv = tid >> 6;
    int bid = blockIdx.x;

    if (bid >= 512) {
        // ---- tail-weight prep: 64x64 LDS transpose tiles, 1024 threads
        int t2 = bid - 512;
        int m = t2 >> 4;                      // 0 -> Whb, 1 -> Wopb
        int sub = t2 & 15;
        int oT = (sub & 3) * 64, cT = (sub >> 2) * 64;
        int ct = tid & 63, rb = tid >> 6;     // rb 0..15
#pragma unroll
        for (int i = 0; i < 4; ++i) {
            int r = rb * 4 + i;               // c within tile
            int c = cT + r, o = oT + ct;
            float v;
            if (m == 1) v = opw[c * CC + o];
            else v = (o < 144) ? offw[c * 144 + o]
                   : (o < 216) ? maskw[c * 72 + (o - 144)] : 0.f;
            tile[r * 65 + ct] = v;
        }
        __syncthreads();
        short* dst = (m == 0) ? Whb : Wopb;
#pragma unroll
        for (int i = 0; i < 4; ++i) {
            int r = rb * 4 + i;               // o within tile
            dst[(size_t)(oT + r) * CC + cT + ct] = f2h(tile[ct * 65 + r]);
        }
        return;
    }

    int pix0 = bid * CT;
    int n = pix0 >> 12, hw0 = pix0 & (HWSZ - 1);
    int n0 = wv * 16;
    const float* xn = x + (size_t)n * CC * HWSZ;
    {
        int c = tid >> 2, i4 = (tid & 3) * 4;
        float4 v = *(const float4*)(xn + (size_t)c * HWSZ + hw0 + i4);
        As[(i4 + 0) * ASTR + c] = f2h(v.x);
        As[(i4 + 1) * ASTR + c] = f2h(v.y);
        As[(i4 + 2) * ASTR + c] = f2h(v.z);
        As[(i4 + 3) * ASTR + c] = f2h(v.w);
    }
    __syncthreads();
    f32x4 acc = (f32x4){0.f, 0.f, 0.f, 0.f};
    gemm1(As, Wc1b, lane, n0, &acc);
    __syncthreads();
    int col = lane & 15, qr = (lane >> 4) * 4;
    int o = n0 + col;
    {
        float sc = sc1[o], sh = sh1[o];
#pragma unroll
        for (int r = 0; r < 4; ++r)
            As[(qr + r) * ASTR + o] = f2h(silu_f(acc[r] * sc + sh));
    }
    __syncthreads();
    // bulk vectorized ybf write from LDS (wave wv owns pixel row wv)
    *(uint2*)(ybf + (size_t)(pix0 + wv) * CC + lane * 4) =
        *(const uint2*)(As + wv * ASTR + lane * 4);
    acc = (f32x4){0.f, 0.f, 0.f, 0.f};
    gemm1(As, Wipb, lane, n0, &acc);
    __syncthreads();    // all waves done reading As (and ybf row copied out)
    {
        float bo = ipb[o];
#pragma unroll
        for (int r = 0; r < 4; ++r)
            As[(qr + r) * ASTR + o] = f2h(acc[r] + bo);
    }
    __syncthreads();
    // bulk vectorized xpb write from LDS
    *(uint2*)(xpb + (size_t)(pix0 + wv) * CC + lane * 4) =
        *(const uint2*)(As + wv * ASTR + lane * 4);
}

// ---------------------------------------------------------------------------
// fused tail on a 16-pixel row tile, 1024 threads (16 waves), XCD-swizzled grid.
// (R5-proven body, unchanged.)
__global__ __launch_bounds__(1024, 8) void k_tail(
        const short* __restrict__ ybf, const short* __restrict__ xpb,
        const float* __restrict__ dwt, const float* __restrict__ dwb,
        const float* __restrict__ lng, const float* __restrict__ lnb,
        const short* __restrict__ Whb, const float* __restrict__ bh,
        const short* __restrict__ Wopb, const float* __restrict__ opb,
        const float* __restrict__ sc2, const float* __restrict__ sh2,
        float* __restrict__ out) {
    __shared__ __align__(16) short As[TT * ASTR];
    __shared__ __align__(16) float buf[TT * 260];   // ml/loff, later xs overlay
    float* ml   = buf;              // 16*96 (stride 12 per group)
    float* loff = buf + 1536;       // 16*144
    float* xs   = buf;              // 16*260 overlay (phase 5+)

    int tid = threadIdx.x, lane = tid & 63, wv = tid >> 6;
    int bid = blockIdx.x;
    int swz = ((bid & 7) << 6) | (bid >> 3);
    int pix0 = swz * TT;
    int n = pix0 >> 12, hw0 = pix0 & (HWSZ - 1);
    int h = hw0 >> 6, w0 = hw0 & 63;          // 16 pixels share row h
    int c0 = lane * 4;
    int n0 = wv * 16;
    int col = lane & 15, qr = (lane >> 4) * 4;

    // ---- phase 1: dw 3x3 + bias + LN + GELU (1 px/wave, 4 ch/lane) -> As (fp16)
    {
        float4 dwbv = *(const float4*)(dwb + c0);
        float4 lngv = *(const float4*)(lng + c0);
        float4 lnbv = *(const float4*)(lnb + c0);
        const short* yn = ybf + (size_t)n * HWSZ * CC;
        int pix = wv;
        int w = w0 + pix;
        float4 acc = dwbv;
        bool inter = (h > 0) && (h < HH - 1) && (w0 > 0) && (w0 < WW - TT);
        if (inter) {
#pragma unroll
            for (int ky = 0; ky < 3; ++ky) {
#pragma unroll
                for (int kx = 0; kx < 3; ++kx) {
                    int t = ky * 3 + kx;
                    float4 wt = *(const float4*)(dwt + t * CC + c0);
                    int idx = ((h + ky - 1) << 6) + (w + kx - 1);
                    float4 yv = h2f4(*(const uint2*)(yn + (size_t)idx * CC + c0));
                    acc.x += yv.x * wt.x;
                    acc.y += yv.y * wt.y;
                    acc.z += yv.z * wt.z;
                    acc.w += yv.w * wt.w;
                }
            }
        } else {
#pragma unroll
            for (int ky = 0; ky < 3; ++ky) {
                int yy = h + ky - 1;
                int yc = min(max(yy, 0), HH - 1);
                float vy = (yy == yc) ? 1.f : 0.f;
#pragma unroll
                for (int kx = 0; kx < 3; ++kx) {
                    int xx = w + kx - 1;
                    int xc = min(max(xx, 0), WW - 1);
                    float vm = vy * ((xx == xc) ? 1.f : 0.f);
                    int t = ky * 3 + kx;
                    float4 wt = *(const float4*)(dwt + t * CC + c0);
                    float4 yv = h2f4(*(const uint2*)(yn + (size_t)((yc << 6) + xc) * CC + c0));
                    acc.x += yv.x * wt.x * vm;
                    acc.y += yv.y * wt.y * vm;
                    acc.z += yv.z * wt.z * vm;
                    acc.w += yv.w * wt.w * vm;
                }
            }
        }
        float s1 = acc.x + acc.y + acc.z + acc.w;
        float s2 = acc.x * acc.x + acc.y * acc.y + acc.z * acc.z + acc.w * acc.w;
#pragma unroll
        for (int off = 32; off > 0; off >>= 1) {
            s1 += __shfl_xor(s1, off);
            s2 += __shfl_xor(s2, off);
        }
        float mu = s1 * (1.f / 256.f);
        float var = s2 * (1.f / 256.f) - mu * mu;
        float rs = rsqrtf(var + 1e-5f);
        float4 zv;
        zv.x = (acc.x - mu) * rs * lngv.x + lnbv.x;
        zv.y = (acc.y - mu) * rs * lngv.y + lnbv.y;
        zv.z = (acc.z - mu) * rs * lngv.z + lnbv.z;
        zv.w = (acc.w - mu) * rs * lngv.w + lnbv.w;
        zv.x = 0.5f * zv.x * (1.f + erff(zv.x * 0.70710678118654752f));
        zv.y = 0.5f * zv.y * (1.f + erff(zv.y * 0.70710678118654752f));
        zv.z = 0.5f * zv.z * (1.f + erff(zv.z * 0.70710678118654752f));
        zv.w = 0.5f * zv.w * (1.f + erff(zv.w * 0.70710678118654752f));
        *(uint2*)(As + pix * ASTR + c0) = make_uint2(h2u(zv.x, zv.y), h2u(zv.z, zv.w));
    }
    __syncthreads();

    // ---- phase 2: heads GEMM -> loff / ml (LDS only)
    {
        f32x4 acc = (f32x4){0.f, 0.f, 0.f, 0.f};
        gemm1(As, Whb, lane, n0, &acc);
        int o = n0 + col;
        float bo = bh[o];
#pragma unroll
        for (int r = 0; r < 4; ++r) {
            float v = acc[r] + bo;
            int pix = qr + r;
            if (o < 144) loff[pix * 144 + o] = v;
            else if (o < 216) {
                int mo = o - 144;
                int mg = (mo * 7282) >> 16;          // mo/9 for mo<72
                ml[pix * 96 + mg * 12 + (mo - mg * 9)] = v;
            }
        }
    }
    __syncthreads();

    // ---- phase 4: softmax + parity-split, 2-tap-batched uint4 gather -> As
    {
        int g   = lane >> 3;             // group 0..7
        int ci  = lane & 7;
        int cq  = ci & 3;                // channel quad (8 ch via uint4)
        int par = ci >> 2;               // tap parity: 0 -> taps 0..4, 1 -> taps 5..8
        int gc0 = g * 32 + cq * 8;       // 8 channels, 16-B aligned
        int pix = wv;
        int w = w0 + pix;
        const float* row = ml + pix * 96 + g * 12;
        float4 r0 = *(const float4*)(row);
        float4 r1 = *(const float4*)(row + 4);
        float e0 = __expf(r0.x), e1 = __expf(r0.y), e2 = __expf(r0.z);
        float e3 = __expf(r0.w), e4 = __expf(r1.x), e5 = __expf(r1.y);
        float e6 = __expf(r1.z), e7 = __expf(r1.w), e8 = __expf(row[8]);
        float inv = 1.f / (e0 + e1 + e2 + e3 + e4 + e5 + e6 + e7 + e8);
        float m0 = (par ? e5 : e0) * inv;
        float m1 = (par ? e6 : e1) * inv;
        float m2 = (par ? e7 : e2) * inv;
        float m3 = (par ? e8 : e3) * inv;
        float m4 = e4 * inv;             // only used by par==0
        const float* lp = loff + pix * 144 + g * 18 + par * 10;
        const short* xpn = xpb + (size_t)n * HWSZ * CC;
        __half2 a0 = u2h(0u), a1 = u2h(0u), a2 = u2h(0u), a3 = u2h(0u);

        auto tapw = [&](float ox, float oy, int tx, int ty, float mval,
                        int& i00, int& i10, int& i01, int& i11,
                        float& w00, float& w10, float& w01, float& w11) {
            float px = (float)(w + tx) + ox;
            float py = (float)(h + ty) + oy;
            float fx = floorf(px), fy = floorf(py);
            float wx1 = px - fx, wy1 = py - fy;
            int x0 = (int)fx, y0 = (int)fy;
            int x1 = x0 + 1, y1 = y0 + 1;
            int xc0 = min(max(x0, 1), WW), xc1 = min(max(x1, 1), WW);
            int yc0 = min(max(y0, 1), HH), yc1 = min(max(y1, 1), HH);
            float vx0 = (x0 == xc0) ? 1.f : 0.f, vx1 = (x1 == xc1) ? 1.f : 0.f;
            float vy0 = (y0 == yc0) ? 1.f : 0.f, vy1 = (y1 == yc1) ? 1.f : 0.f;
            w00 = (1.f - wx1) * (1.f - wy1) * mval * vx0 * vy0;
            w10 = wx1 * (1.f - wy1) * mval * vx1 * vy0;
            w01 = (1.f - wx1) * wy1 * mval * vx0 * vy1;
            w11 = wx1 * wy1 * mval * vx1 * vy1;
            i00 = (((yc0 - 1) << 6) + (xc0 - 1)) * CC + gc0;
            i10 = (((yc0 - 1) << 6) + (xc1 - 1)) * CC + gc0;
            i01 = (((yc1 - 1) << 6) + (xc0 - 1)) * CC + gc0;
            i11 = (((yc1 - 1) << 6) + (xc1 - 1)) * CC + gc0;
        };
        auto fma4 = [&](uint4 u, float wgt) {
            __half2 W = __float2half2_rn(wgt);
            a0 = __hfma2(u2h(u.x), W, a0);
            a1 = __hfma2(u2h(u.y), W, a1);
            a2 = __hfma2(u2h(u.z), W, a2);
            a3 = __hfma2(u2h(u.w), W, a3);
        };

        int A00, A10, A01, A11, B00, B10, B01, B11;
        float Wa0, Wa1, Wa2, Wa3, Wb0, Wb1, Wb2, Wb3;
        // pair 1: taps {0,1} (par0) / {5,6} (par1)
        float2 ofa = *(const float2*)(lp + 0);
        float2 ofb = *(const float2*)(lp + 2);
        tapw(ofa.x, ofa.y, par ? 1 : 0, par ? 2 : 0, m0, A00, A10, A01, A11, Wa0, Wa1, Wa2, Wa3);
        tapw(ofb.x, ofb.y, par ? 2 : 0, par ? 0 : 1, m1, B00, B10, B01, B11, Wb0, Wb1, Wb2, Wb3);
        {
            uint4 uA0 = *(const uint4*)(xpn + A00);
            uint4 uA1 = *(const uint4*)(xpn + A10);
            uint4 uA2 = *(const uint4*)(xpn + A01);
            uint4 uA3 = *(const uint4*)(xpn + A11);
            uint4 uB0 = *(const uint4*)(xpn + B00);
            uint4 uB1 = *(const uint4*)(xpn + B10);
            uint4 uB2 = *(const uint4*)(xpn + B01);
            uint4 uB3 = *(const uint4*)(xpn + B11);
            fma4(uA0, Wa0); fma4(uA1, Wa1); fma4(uA2, Wa2); fma4(uA3, Wa3);
            fma4(uB0, Wb0); fma4(uB1, Wb1); fma4(uB2, Wb2); fma4(uB3, Wb3);
        }
        // pair 2: taps {2,3} (par0) / {7,8} (par1)
        ofa = *(const float2*)(lp + 4);
        ofb = *(const float2*)(lp + 6);
        tapw(ofa.x, ofa.y, par ? 2 : 0, par ? 1 : 2, m2, A00, A10, A01, A11, Wa0, Wa1, Wa2, Wa3);
        tapw(ofb.x, ofb.y, par ? 2 : 1, par ? 2 : 0, m3, B00, B10, B01, B11, Wb0, Wb1, Wb2, Wb3);
        {
            uint4 uA0 = *(const uint4*)(xpn + A00);
            uint4 uA1 = *(const uint4*)(xpn + A10);
            uint4 uA2 = *(const uint4*)(xpn + A01);
            uint4 uA3 = *(const uint4*)(xpn + A11);
            uint4 uB0 = *(const uint4*)(xpn + B00);
            uint4 uB1 = *(const uint4*)(xpn + B10);
            uint4 uB2 = *(const uint4*)(xpn + B01);
            uint4 uB3 = *(const uint4*)(xpn + B11);
            fma4(uA0, Wa0); fma4(uA1, Wa1); fma4(uA2, Wa2); fma4(uA3, Wa3);
            fma4(uB0, Wb0); fma4(uB1, Wb1); fma4(uB2, Wb2); fma4(uB3, Wb3);
        }
        // tap 4 (center), par==0 only
        if (!par) {
            ofa = *(const float2*)(lp + 8);
            tapw(ofa.x, ofa.y, 1, 1, m4, A00, A10, A01, A11, Wa0, Wa1, Wa2, Wa3);
            uint4 uA0 = *(const uint4*)(xpn + A00);
            uint4 uA1 = *(const uint4*)(xpn + A10);
            uint4 uA2 = *(const uint4*)(xpn + A01);
            uint4 uA3 = *(const uint4*)(xpn + A11);
            fma4(uA0, Wa0); fma4(uA1, Wa1); fma4(uA2, Wa2); fma4(uA3, Wa3);
        }
        // combine tap parities (lane ci and ci^4 hold partials of same channels)
        a0 = __hadd2(a0, u2h((unsigned)__shfl_xor((int)h2raw(a0), 4)));
        a1 = __hadd2(a1, u2h((unsigned)__shfl_xor((int)h2raw(a1), 4)));
        a2 = __hadd2(a2, u2h((unsigned)__shfl_xor((int)h2raw(a2), 4)));
        a3 = __hadd2(a3, u2h((unsigned)__shfl_xor((int)h2raw(a3), 4)));
        if (!par)
            *(uint4*)(As + pix * ASTR + gc0) =
                make_uint4(h2raw(a0), h2raw(a1), h2raw(a2), h2raw(a3));
    }
    __syncthreads();    // As v2 ready; ml/loff fully consumed

    // ---- phase 5: outproj GEMM + BN2 + SiLU -> xs (overlay of ml/loff)
    {
        f32x4 acc = (f32x4){0.f, 0.f, 0.f, 0.f};
        gemm1(As, Wopb, lane, n0, &acc);
        int o = n0 + col;
        float bo = opb[o], sc = sc2[o], sh = sh2[o];
#pragma unroll
        for (int r = 0; r < 4; ++r)
            xs[(qr + r) * 260 + o] = silu_f((acc[r] + bo) * sc + sh);
    }
    __syncthreads();

    // ---- store NCHW: 4 lanes cover one channel's 16 pixels = one 64-B line
    {
        int i4 = (tid & 3) * 4;
        int o = tid >> 2;                 // 0..255
        float* on = out + (size_t)n * CC * HWSZ + hw0 + i4;
        float4 ov;
        ov.x = xs[(i4 + 0) * 260 + o];
        ov.y = xs[(i4 + 1) * 260 + o];
        ov.z = xs[(i4 + 2) * 260 + o];
        ov.w = xs[(i4 + 3) * 260 + o];
        *(float4*)(on + (size_t)o * HWSZ) = ov;
    }
}

// ---------------------------------------------------------------------------
extern "C" void kernel_launch(void* const* d_in, const int* in_sizes, int n_in,
                              void* d_out, int out_size, void* d_ws, size_t ws_size,
                              hipStream_t stream) {
    const float* x        = (const float*)d_in[0];
    const float* conv1_w  = (const float*)d_in[1];
    const float* bn1_g    = (const float*)d_in[2];
    const float* bn1_b    = (const float*)d_in[3];
    const float* bn1_m    = (const float*)d_in[4];
    const float* bn1_v    = (const float*)d_in[5];
    const float* inproj_w = (const float*)d_in[6];
    const float* inproj_b = (const float*)d_in[7];
    const float* dw_w     = (const float*)d_in[8];
    const float* dw_b     = (const float*)d_in[9];
    const float* ln_g     = (const float*)d_in[10];
    const float* ln_b     = (const float*)d_in[11];
    const float* off_w    = (const float*)d_in[12];
    const float* off_b    = (const float*)d_in[13];
    const float* mask_w   = (const float*)d_in[14];
    const float* mask_b   = (const float*)d_in[15];
    const float* outproj_w = (const float*)d_in[16];
    const float* outproj_b = (const float*)d_in[17];
    const float* bn2_g    = (const float*)d_in[18];
    const float* bn2_b    = (const float*)d_in[19];
    const float* bn2_m    = (const float*)d_in[20];
    const float* bn2_v    = (const float*)d_in[21];
    float* out = (float*)d_out;

    short* Wc1b = (short*)d_ws;            // 65536 shorts each
    short* Wipb = Wc1b + 65536;
    short* Whb  = Wipb + 65536;
    short* Wopb = Whb + 65536;
    float* fp   = (float*)(Wopb + 65536);
    float* dwt  = fp;                      // 9*256
    float* bh   = dwt + 9 * CC;
    float* sc1  = bh + 256;
    float* sh1  = sc1 + 256;
    float* sc2  = sh1 + 256;
    float* sh2  = sc2 + 256;
    short* ybf  = (short*)(sh2 + 256);     // NPIX*CC fp16 (NHWC)
    short* xpb  = ybf + (size_t)NPIX * CC; // NPIX*CC fp16 (NHWC)

    k_prepA<<<dim3(21), dim3(256), 0, stream>>>(conv1_w, inproj_w, dw_w,
                                                off_b, mask_b, bn1_g, bn1_b, bn1_m, bn1_v,
                                                bn2_g, bn2_b, bn2_m, bn2_v,
                                                Wc1b, Wipb, dwt, bh, sc1, sh1, sc2, sh2);
    k_conv_in<<<dim3(544), dim3(1024), 0, stream>>>(x, Wc1b, Wipb, sc1, sh1, inproj_b,
                                                    off_w, mask_w, outproj_w, Whb, Wopb,
                                                    ybf, xpb);
    k_tail<<<dim3(NPIX / TT), dim3(1024), 0, stream>>>(ybf, xpb, dwt, dw_b, ln_g, ln_b,
                                                       Whb, bh, Wopb, outproj_b, sc2, sh2, out);
}

// Round 11
// 147.295 us; speedup vs baseline: 1.0737x; 1.0737x over previous
//
#include <hip/hip_runtime.h>
#include <hip/hip_fp16.h>
#include <math.h>

// Problem constants (N=2, C=256, H=W=64, G=8, P=9, CG=32)
#define CC    256
#define HH    64
#define WW    64
#define HWSZ  4096
#define NPIX  8192
#define MT    32        // conv_in tile (pixels)
#define TT    16        // tail tile (pixels)
#define ASTR  264       // A-tile LDS row stride in fp16 elems (528 B)

typedef __attribute__((ext_vector_type(8))) _Float16 half8;
typedef __attribute__((ext_vector_type(4))) float f32x4;

__device__ __forceinline__ float silu_f(float x) { return x / (1.f + __expf(-x)); }

// fp32 -> fp16 (RNE), as raw short
__device__ __forceinline__ short f2h(float f) {
    __half h = __float2half(f);
    return *reinterpret_cast<short*>(&h);
}
__device__ __forceinline__ unsigned h2u(float a, float b) {
    __half2 h = __floats2half2_rn(a, b);
    return *reinterpret_cast<unsigned*>(&h);
}
__device__ __forceinline__ __half2 u2h(unsigned v) { return *reinterpret_cast<__half2*>(&v); }
__device__ __forceinline__ unsigned h2raw(__half2 h) { return *reinterpret_cast<unsigned*>(&h); }
// 4 packed fp16 -> float4
__device__ __forceinline__ float4 h2f4(uint2 u) {
    float2 a = __half22float2(u2h(u.x));
    float2 b = __half22float2(u2h(u.y));
    return make_float4(a.x, a.y, b.x, b.y);
}

// ---------------------------------------------------------------------------
// prepA: ONLY what k_conv_in needs (Wipb transpose, Wc1b copy, all scalars).
// 21 blocks x 256 threads.
__global__ __launch_bounds__(256) void k_prepA(
        const float* __restrict__ cw, const float* __restrict__ ipw,
        const float* __restrict__ dww,
        const float* __restrict__ offb, const float* __restrict__ maskb,
        const float* __restrict__ g1, const float* __restrict__ b1,
        const float* __restrict__ m1, const float* __restrict__ v1,
        const float* __restrict__ g2, const float* __restrict__ b2,
        const float* __restrict__ m2, const float* __restrict__ v2,
        short* __restrict__ Wc1b, short* __restrict__ Wipb,
        float* __restrict__ dwt,
        float* __restrict__ bh, float* __restrict__ sc1, float* __restrict__ sh1,
        float* __restrict__ sc2, float* __restrict__ sh2) {
    __shared__ float tile[64 * 65];
    int t = threadIdx.x, bt = blockIdx.x;
    int ct = t & 63, rb = t >> 6;             // rb 0..3
    if (bt < 16) {
        int sub = bt;
        int oT = (sub & 3) * 64, cT = (sub >> 2) * 64;
#pragma unroll
        for (int i = 0; i < 16; ++i) {
            int r = rb * 16 + i;              // c within tile
            tile[r * 65 + ct] = ipw[(cT + r) * CC + oT + ct];
        }
        __syncthreads();
#pragma unroll
        for (int i = 0; i < 16; ++i) {
            int r = rb * 16 + i;              // o within tile
            Wipb[(size_t)(oT + r) * CC + cT + ct] = f2h(tile[ct * 65 + r]);
        }
    } else if (bt < 20) {
        // Wc1b straight copy: 4 blocks x 16 iters x 256 thr x 4 = 65536
        int base = (bt - 16) * 16384;
#pragma unroll
        for (int i = 0; i < 16; ++i) {
            int idx = base + i * 1024 + t * 4;
            float4 v = *(const float4*)(cw + idx);
            *(uint2*)(Wc1b + idx) = make_uint2(h2u(v.x, v.y), h2u(v.z, v.w));
        }
    } else {
        int c = t;
#pragma unroll
        for (int j = 0; j < 9; ++j)
            dwt[j * CC + c] = dww[c * 9 + j];   // writes coalesced across lanes
        float bv = 0.f;
        if (c < 144) bv = offb[c];
        else if (c < 216) bv = maskb[c - 144];
        bh[c] = bv;
        float s1 = g1[c] * rsqrtf(v1[c] + 1e-3f);
        sc1[c] = s1; sh1[c] = b1[c] - m1[c] * s1;
        float s2 = g2[c] * rsqrtf(v2[c] + 1e-5f);
        sc2[c] = s2; sh2[c] = b2[c] - m2[c] * s2;
    }
}

// ---------------------------------------------------------------------------
// wave-level GEMM (fp16): 1 n-tile (16 outputs) per wave, K=256, A rows 0..15 in LDS
__device__ __forceinline__ void gemm1(const short* As, const short* __restrict__ Wb,
                                      int lane, int n0, f32x4* acc) {
    const int m = lane & 15, q = lane >> 4;
#pragma unroll
    for (int kk = 0; kk < 8; ++kk) {
        int c0 = kk * 32 + q * 8;
        half8 a = *(const half8*)(As + m * ASTR + c0);
        half8 b = *(const half8*)(Wb + (size_t)(n0 + m) * CC + c0);
        *acc = __builtin_amdgcn_mfma_f32_16x16x32_f16(a, b, *acc, 0, 0, 0);
    }
}

// ---------------------------------------------------------------------------
// conv1(1x1) + BN1 + SiLU -> ybf ; fused inproj -> xpb. Blocks 0..255: conv.
// Blocks 256..287: piggy-backed prep of TAIL-ONLY weights (Whb/Wopb transposes)
// — ordered before k_tail by the kernel boundary, concurrent with conv here.
__global__ __launch_bounds__(1024, 8) void k_conv_in(
        const float* __restrict__ x, const short* __restrict__ Wc1b,
        const short* __restrict__ Wipb, const float* __restrict__ sc1,
        const float* __restrict__ sh1, const float* __restrict__ ipb,
        const float* __restrict__ offw, const float* __restrict__ maskw,
        const float* __restrict__ opw,
        short* __restrict__ Whb, short* __restrict__ Wopb,
        short* __restrict__ ybf, short* __restrict__ xpb) {
    __shared__ __align__(16) short As[MT * ASTR];
    __shared__ float tile[64 * 65];
    int tid = threadIdx.x, lane = tid & 63, wv = tid >> 6;
    int bid = blockIdx.x;

    if (bid >= 256) {
        // ---- tail-weight prep: 64x64 LDS transpose tiles, 1024 threads
        int t2 = bid - 256;
        int m = t2 >> 4;                      // 0 -> Whb, 1 -> Wopb
        int sub = t2 & 15;
        int oT = (sub & 3) * 64, cT = (sub >> 2) * 64;
        int ct = tid & 63, rb = tid >> 6;     // rb 0..15
#pragma unroll
        for (int i = 0; i < 4; ++i) {
            int r = rb * 4 + i;               // c within tile
            int c = cT + r, o = oT + ct;
            float v;
            if (m == 1) v = opw[c * CC + o];
            else v = (o < 144) ? offw[c * 144 + o]
                   : (o < 216) ? maskw[c * 72 + (o - 144)] : 0.f;
            tile[r * 65 + ct] = v;
        }
        __syncthreads();
        short* dst = (m == 0) ? Whb : Wopb;
#pragma unroll
        for (int i = 0; i < 4; ++i) {
            int r = rb * 4 + i;               // o within tile
            dst[(size_t)(oT + r) * CC + cT + ct] = f2h(tile[ct * 65 + r]);
        }
        return;
    }

    int pix0 = bid * MT;
    int n = pix0 >> 12, hw0 = pix0 & (HWSZ - 1);
    int n0 = wv * 16;
    const float* xn = x + (size_t)n * CC * HWSZ;
#pragma unroll
    for (int rep = 0; rep < 2; ++rep) {
        int f = tid + rep * 1024;
        int c = f >> 3, i8 = (f & 7) * 4;
        float4 v = *(const float4*)(xn + (size_t)c * HWSZ + hw0 + i8);
        As[(i8 + 0) * ASTR + c] = f2h(v.x);
        As[(i8 + 1) * ASTR + c] = f2h(v.y);
        As[(i8 + 2) * ASTR + c] = f2h(v.z);
        As[(i8 + 3) * ASTR + c] = f2h(v.w);
    }
    __syncthreads();
    f32x4 acc0 = (f32x4){0.f, 0.f, 0.f, 0.f};
    f32x4 acc1 = (f32x4){0.f, 0.f, 0.f, 0.f};
    gemm1(As, Wc1b, lane, n0, &acc0);
    gemm1(As + 16 * ASTR, Wc1b, lane, n0, &acc1);
    __syncthreads();
    int col = lane & 15, qr = (lane >> 4) * 4;
    int o = n0 + col;
    {
        float sc = sc1[o], sh = sh1[o];
#pragma unroll
        for (int r = 0; r < 4; ++r) {
            short v0 = f2h(silu_f(acc0[r] * sc + sh));
            As[(qr + r) * ASTR + o] = v0;
            ybf[(size_t)(pix0 + qr + r) * CC + o] = v0;
            short v1 = f2h(silu_f(acc1[r] * sc + sh));
            As[(16 + qr + r) * ASTR + o] = v1;
            ybf[(size_t)(pix0 + 16 + qr + r) * CC + o] = v1;
        }
    }
    __syncthreads();
    acc0 = (f32x4){0.f, 0.f, 0.f, 0.f};
    acc1 = (f32x4){0.f, 0.f, 0.f, 0.f};
    gemm1(As, Wipb, lane, n0, &acc0);
    gemm1(As + 16 * ASTR, Wipb, lane, n0, &acc1);
    {
        float bo = ipb[o];
#pragma unroll
        for (int r = 0; r < 4; ++r) {
            xpb[(size_t)(pix0 + qr + r) * CC + o] = f2h(acc0[r] + bo);
            xpb[(size_t)(pix0 + 16 + qr + r) * CC + o] = f2h(acc1[r] + bo);
        }
    }
}

// ---------------------------------------------------------------------------
// fused tail on a 16-pixel row tile, 1024 threads (16 waves), XCD-swizzled grid.
// (R5-proven body, unchanged.)
__global__ __launch_bounds__(1024, 8) void k_tail(
        const short* __restrict__ ybf, const short* __restrict__ xpb,
        const float* __restrict__ dwt, const float* __restrict__ dwb,
        const float* __restrict__ lng, const float* __restrict__ lnb,
        const short* __restrict__ Whb, const float* __restrict__ bh,
        const short* __restrict__ Wopb, const float* __restrict__ opb,
        const float* __restrict__ sc2, const float* __restrict__ sh2,
        float* __restrict__ out) {
    __shared__ __align__(16) short As[TT * ASTR];
    __shared__ __align__(16) float buf[TT * 260];   // ml/loff, later xs overlay
    float* ml   = buf;              // 16*96 (stride 12 per group)
    float* loff = buf + 1536;       // 16*144
    float* xs   = buf;              // 16*260 overlay (phase 5+)

    int tid = threadIdx.x, lane = tid & 63, wv = tid >> 6;
    int bid = blockIdx.x;
    int swz = ((bid & 7) << 6) | (bid >> 3);
    int pix0 = swz * TT;
    int n = pix0 >> 12, hw0 = pix0 & (HWSZ - 1);
    int h = hw0 >> 6, w0 = hw0 & 63;          // 16 pixels share row h
    int c0 = lane * 4;
    int n0 = wv * 16;
    int col = lane & 15, qr = (lane >> 4) * 4;

    // ---- phase 1: dw 3x3 + bias + LN + GELU (1 px/wave, 4 ch/lane) -> As (fp16)
    {
        float4 dwbv = *(const float4*)(dwb + c0);
        float4 lngv = *(const float4*)(lng + c0);
        float4 lnbv = *(const float4*)(lnb + c0);
        const short* yn = ybf + (size_t)n * HWSZ * CC;
        int pix = wv;
        int w = w0 + pix;
        float4 acc = dwbv;
        bool inter = (h > 0) && (h < HH - 1) && (w0 > 0) && (w0 < WW - TT);
        if (inter) {
#pragma unroll
            for (int ky = 0; ky < 3; ++ky) {
#pragma unroll
                for (int kx = 0; kx < 3; ++kx) {
                    int t = ky * 3 + kx;
                    float4 wt = *(const float4*)(dwt + t * CC + c0);
                    int idx = ((h + ky - 1) << 6) + (w + kx - 1);
                    float4 yv = h2f4(*(const uint2*)(yn + (size_t)idx * CC + c0));
                    acc.x += yv.x * wt.x;
                    acc.y += yv.y * wt.y;
                    acc.z += yv.z * wt.z;
                    acc.w += yv.w * wt.w;
                }
            }
        } else {
#pragma unroll
            for (int ky = 0; ky < 3; ++ky) {
                int yy = h + ky - 1;
                int yc = min(max(yy, 0), HH - 1);
                float vy = (yy == yc) ? 1.f : 0.f;
#pragma unroll
                for (int kx = 0; kx < 3; ++kx) {
                    int xx = w + kx - 1;
                    int xc = min(max(xx, 0), WW - 1);
                    float vm = vy * ((xx == xc) ? 1.f : 0.f);
                    int t = ky * 3 + kx;
                    float4 wt = *(const float4*)(dwt + t * CC + c0);
                    float4 yv = h2f4(*(const uint2*)(yn + (size_t)((yc << 6) + xc) * CC + c0));
                    acc.x += yv.x * wt.x * vm;
                    acc.y += yv.y * wt.y * vm;
                    acc.z += yv.z * wt.z * vm;
                    acc.w += yv.w * wt.w * vm;
                }
            }
        }
        float s1 = acc.x + acc.y + acc.z + acc.w;
        float s2 = acc.x * acc.x + acc.y * acc.y + acc.z * acc.z + acc.w * acc.w;
#pragma unroll
        for (int off = 32; off > 0; off >>= 1) {
            s1 += __shfl_xor(s1, off);
            s2 += __shfl_xor(s2, off);
        }
        float mu = s1 * (1.f / 256.f);
        float var = s2 * (1.f / 256.f) - mu * mu;
        float rs = rsqrtf(var + 1e-5f);
        float4 zv;
        zv.x = (acc.x - mu) * rs * lngv.x + lnbv.x;
        zv.y = (acc.y - mu) * rs * lngv.y + lnbv.y;
        zv.z = (acc.z - mu) * rs * lngv.z + lnbv.z;
        zv.w = (acc.w - mu) * rs * lngv.w + lnbv.w;
        zv.x = 0.5f * zv.x * (1.f + erff(zv.x * 0.70710678118654752f));
        zv.y = 0.5f * zv.y * (1.f + erff(zv.y * 0.70710678118654752f));
        zv.z = 0.5f * zv.z * (1.f + erff(zv.z * 0.70710678118654752f));
        zv.w = 0.5f * zv.w * (1.f + erff(zv.w * 0.70710678118654752f));
        *(uint2*)(As + pix * ASTR + c0) = make_uint2(h2u(zv.x, zv.y), h2u(zv.z, zv.w));
    }
    __syncthreads();

    // ---- phase 2: heads GEMM -> loff / ml (LDS only)
    {
        f32x4 acc = (f32x4){0.f, 0.f, 0.f, 0.f};
        gemm1(As, Whb, lane, n0, &acc);
        int o = n0 + col;
        float bo = bh[o];
#pragma unroll
        for (int r = 0; r < 4; ++r) {
            float v = acc[r] + bo;
            int pix = qr + r;
            if (o < 144) loff[pix * 144 + o] = v;
            else if (o < 216) {
                int mo = o - 144;
                int mg = (mo * 7282) >> 16;          // mo/9 for mo<72
                ml[pix * 96 + mg * 12 + (mo - mg * 9)] = v;
            }
        }
    }
    __syncthreads();

    // ---- phase 4: softmax + parity-split, 2-tap-batched uint4 gather -> As
    {
        int g   = lane >> 3;             // group 0..7
        int ci  = lane & 7;
        int cq  = ci & 3;                // channel quad (8 ch via uint4)
        int par = ci >> 2;               // tap parity: 0 -> taps 0..4, 1 -> taps 5..8
        int gc0 = g * 32 + cq * 8;       // 8 channels, 16-B aligned
        int pix = wv;
        int w = w0 + pix;
        const float* row = ml + pix * 96 + g * 12;
        float4 r0 = *(const float4*)(row);
        float4 r1 = *(const float4*)(row + 4);
        float e0 = __expf(r0.x), e1 = __expf(r0.y), e2 = __expf(r0.z);
        float e3 = __expf(r0.w), e4 = __expf(r1.x), e5 = __expf(r1.y);
        float e6 = __expf(r1.z), e7 = __expf(r1.w), e8 = __expf(row[8]);
        float inv = 1.f / (e0 + e1 + e2 + e3 + e4 + e5 + e6 + e7 + e8);
        float m0 = (par ? e5 : e0) * inv;
        float m1 = (par ? e6 : e1) * inv;
        float m2 = (par ? e7 : e2) * inv;
        float m3 = (par ? e8 : e3) * inv;
        float m4 = e4 * inv;             // only used by par==0
        const float* lp = loff + pix * 144 + g * 18 + par * 10;
        const short* xpn = xpb + (size_t)n * HWSZ * CC;
        __half2 a0 = u2h(0u), a1 = u2h(0u), a2 = u2h(0u), a3 = u2h(0u);

        auto tapw = [&](float ox, float oy, int tx, int ty, float mval,
                        int& i00, int& i10, int& i01, int& i11,
                        float& w00, float& w10, float& w01, float& w11) {
            float px = (float)(w + tx) + ox;
            float py = (float)(h + ty) + oy;
            float fx = floorf(px), fy = floorf(py);
            float wx1 = px - fx, wy1 = py - fy;
            int x0 = (int)fx, y0 = (int)fy;
            int x1 = x0 + 1, y1 = y0 + 1;
            int xc0 = min(max(x0, 1), WW), xc1 = min(max(x1, 1), WW);
            int yc0 = min(max(y0, 1), HH), yc1 = min(max(y1, 1), HH);
            float vx0 = (x0 == xc0) ? 1.f : 0.f, vx1 = (x1 == xc1) ? 1.f : 0.f;
            float vy0 = (y0 == yc0) ? 1.f : 0.f, vy1 = (y1 == yc1) ? 1.f : 0.f;
            w00 = (1.f - wx1) * (1.f - wy1) * mval * vx0 * vy0;
            w10 = wx1 * (1.f - wy1) * mval * vx1 * vy0;
            w01 = (1.f - wx1) * wy1 * mval * vx0 * vy1;
            w11 = wx1 * wy1 * mval * vx1 * vy1;
            i00 = (((yc0 - 1) << 6) + (xc0 - 1)) * CC + gc0;
            i10 = (((yc0 - 1) << 6) + (xc1 - 1)) * CC + gc0;
            i01 = (((yc1 - 1) << 6) + (xc0 - 1)) * CC + gc0;
            i11 = (((yc1 - 1) << 6) + (xc1 - 1)) * CC + gc0;
        };
        auto fma4 = [&](uint4 u, float wgt) {
            __half2 W = __float2half2_rn(wgt);
            a0 = __hfma2(u2h(u.x), W, a0);
            a1 = __hfma2(u2h(u.y), W, a1);
            a2 = __hfma2(u2h(u.z), W, a2);
            a3 = __hfma2(u2h(u.w), W, a3);
        };

        int A00, A10, A01, A11, B00, B10, B01, B11;
        float Wa0, Wa1, Wa2, Wa3, Wb0, Wb1, Wb2, Wb3;
        // pair 1: taps {0,1} (par0) / {5,6} (par1)
        float2 ofa = *(const float2*)(lp + 0);
        float2 ofb = *(const float2*)(lp + 2);
        tapw(ofa.x, ofa.y, par ? 1 : 0, par ? 2 : 0, m0, A00, A10, A01, A11, Wa0, Wa1, Wa2, Wa3);
        tapw(ofb.x, ofb.y, par ? 2 : 0, par ? 0 : 1, m1, B00, B10, B01, B11, Wb0, Wb1, Wb2, Wb3);
        {
            uint4 uA0 = *(const uint4*)(xpn + A00);
            uint4 uA1 = *(const uint4*)(xpn + A10);
            uint4 uA2 = *(const uint4*)(xpn + A01);
            uint4 uA3 = *(const uint4*)(xpn + A11);
            uint4 uB0 = *(const uint4*)(xpn + B00);
            uint4 uB1 = *(const uint4*)(xpn + B10);
            uint4 uB2 = *(const uint4*)(xpn + B01);
            uint4 uB3 = *(const uint4*)(xpn + B11);
            fma4(uA0, Wa0); fma4(uA1, Wa1); fma4(uA2, Wa2); fma4(uA3, Wa3);
            fma4(uB0, Wb0); fma4(uB1, Wb1); fma4(uB2, Wb2); fma4(uB3, Wb3);
        }
        // pair 2: taps {2,3} (par0) / {7,8} (par1)
        ofa = *(const float2*)(lp + 4);
        ofb = *(const float2*)(lp + 6);
        tapw(ofa.x, ofa.y, par ? 2 : 0, par ? 1 : 2, m2, A00, A10, A01, A11, Wa0, Wa1, Wa2, Wa3);
        tapw(ofb.x, ofb.y, par ? 2 : 1, par ? 2 : 0, m3, B00, B10, B01, B11, Wb0, Wb1, Wb2, Wb3);
        {
            uint4 uA0 = *(const uint4*)(xpn + A00);
            uint4 uA1 = *(const uint4*)(xpn + A10);
            uint4 uA2 = *(const uint4*)(xpn + A01);
            uint4 uA3 = *(const uint4*)(xpn + A11);
            uint4 uB0 = *(const uint4*)(xpn + B00);
            uint4 uB1 = *(const uint4*)(xpn + B10);
            uint4 uB2 = *(const uint4*)(xpn + B01);
            uint4 uB3 = *(const uint4*)(xpn + B11);
            fma4(uA0, Wa0); fma4(uA1, Wa1); fma4(uA2, Wa2); fma4(uA3, Wa3);
            fma4(uB0, Wb0); fma4(uB1, Wb1); fma4(uB2, Wb2); fma4(uB3, Wb3);
        }
        // tap 4 (center), par==0 only
        if (!par) {
            ofa = *(const float2*)(lp + 8);
            tapw(ofa.x, ofa.y, 1, 1, m4, A00, A10, A01, A11, Wa0, Wa1, Wa2, Wa3);
            uint4 uA0 = *(const uint4*)(xpn + A00);
            uint4 uA1 = *(const uint4*)(xpn + A10);
            uint4 uA2 = *(const uint4*)(xpn + A01);
            uint4 uA3 = *(const uint4*)(xpn + A11);
            fma4(uA0, Wa0); fma4(uA1, Wa1); fma4(uA2, Wa2); fma4(uA3, Wa3);
        }
        // combine tap parities (lane ci and ci^4 hold partials of same channels)
        a0 = __hadd2(a0, u2h((unsigned)__shfl_xor((int)h2raw(a0), 4)));
        a1 = __hadd2(a1, u2h((unsigned)__shfl_xor((int)h2raw(a1), 4)));
        a2 = __hadd2(a2, u2h((unsigned)__shfl_xor((int)h2raw(a2), 4)));
        a3 = __hadd2(a3, u2h((unsigned)__shfl_xor((int)h2raw(a3), 4)));
        if (!par)
            *(uint4*)(As + pix * ASTR + gc0) =
                make_uint4(h2raw(a0), h2raw(a1), h2raw(a2), h2raw(a3));
    }
    __syncthreads();    // As v2 ready; ml/loff fully consumed

    // ---- phase 5: outproj GEMM + BN2 + SiLU -> xs (overlay of ml/loff)
    {
        f32x4 acc = (f32x4){0.f, 0.f, 0.f, 0.f};
        gemm1(As, Wopb, lane, n0, &acc);
        int o = n0 + col;
        float bo = opb[o], sc = sc2[o], sh = sh2[o];
#pragma unroll
        for (int r = 0; r < 4; ++r)
            xs[(qr + r) * 260 + o] = silu_f((acc[r] + bo) * sc + sh);
    }
    __syncthreads();

    // ---- store NCHW: 4 lanes cover one channel's 16 pixels = one 64-B line
    {
        int i4 = (tid & 3) * 4;
        int o = tid >> 2;                 // 0..255
        float* on = out + (size_t)n * CC * HWSZ + hw0 + i4;
        float4 ov;
        ov.x = xs[(i4 + 0) * 260 + o];
        ov.y = xs[(i4 + 1) * 260 + o];
        ov.z = xs[(i4 + 2) * 260 + o];
        ov.w = xs[(i4 + 3) * 260 + o];
        *(float4*)(on + (size_t)o * HWSZ) = ov;
    }
}

// ---------------------------------------------------------------------------
extern "C" void kernel_launch(void* const* d_in, const int* in_sizes, int n_in,
                              void* d_out, int out_size, void* d_ws, size_t ws_size,
                              hipStream_t stream) {
    const float* x        = (const float*)d_in[0];
    const float* conv1_w  = (const float*)d_in[1];
    const float* bn1_g    = (const float*)d_in[2];
    const float* bn1_b    = (const float*)d_in[3];
    const float* bn1_m    = (const float*)d_in[4];
    const float* bn1_v    = (const float*)d_in[5];
    const float* inproj_w = (const float*)d_in[6];
    const float* inproj_b = (const float*)d_in[7];
    const float* dw_w     = (const float*)d_in[8];
    const float* dw_b     = (const float*)d_in[9];
    const float* ln_g     = (const float*)d_in[10];
    const float* ln_b     = (const float*)d_in[11];
    const float* off_w    = (const float*)d_in[12];
    const float* off_b    = (const float*)d_in[13];
    const float* mask_w   = (const float*)d_in[14];
    const float* mask_b   = (const float*)d_in[15];
    const float* outproj_w = (const float*)d_in[16];
    const float* outproj_b = (const float*)d_in[17];
    const float* bn2_g    = (const float*)d_in[18];
    const float* bn2_b    = (const float*)d_in[19];
    const float* bn2_m    = (const float*)d_in[20];
    const float* bn2_v    = (const float*)d_in[21];
    float* out = (float*)d_out;

    short* Wc1b = (short*)d_ws;            // 65536 shorts each
    short* Wipb = Wc1b + 65536;
    short* Whb  = Wipb + 65536;
    short* Wopb = Whb + 65536;
    float* fp   = (float*)(Wopb + 65536);
    float* dwt  = fp;                      // 9*256
    float* bh   = dwt + 9 * CC;
    float* sc1  = bh + 256;
    float* sh1  = sc1 + 256;
    float* sc2  = sh1 + 256;
    float* sh2  = sc2 + 256;
    short* ybf  = (short*)(sh2 + 256);     // NPIX*CC fp16 (NHWC)
    short* xpb  = ybf + (size_t)NPIX * CC; // NPIX*CC fp16 (NHWC)

    k_prepA<<<dim3(21), dim3(256), 0, stream>>>(conv1_w, inproj_w, dw_w,
                                                off_b, mask_b, bn1_g, bn1_b, bn1_m, bn1_v,
                                                bn2_g, bn2_b, bn2_m, bn2_v,
                                                Wc1b, Wipb, dwt, bh, sc1, sh1, sc2, sh2);
    k_conv_in<<<dim3(288), dim3(1024), 0, stream>>>(x, Wc1b, Wipb, sc1, sh1, inproj_b,
                                                    off_w, mask_w, outproj_w, Whb, Wopb,
                                                    ybf, xpb);
    k_tail<<<dim3(NPIX / TT), dim3(1024), 0, stream>>>(ybf, xpb, dwt, dw_b, ln_g, ln_b,
                                                       Whb, bh, Wopb, outproj_b, sc2, sh2, out);
}